// Round 5
// baseline (901.556 us; speedup 1.0000x reference)
//
#include <hip/hip_runtime.h>
#include <math.h>

// Problem constants: B=4, C=256, H=W=64 -> HW=4096
#define HW 4096
#define NC 256
#define NB 4
#define EPSF 1e-5f
#define TEN (NB * HW * NC)  // elements per output tensor = 4194304

typedef _Float16 half8 __attribute__((ext_vector_type(8)));
typedef _Float16 half4v __attribute__((ext_vector_type(4)));
typedef float f32x4 __attribute__((ext_vector_type(4)));

// ws layout (bytes):
//  [0, 16K)   stats f32: meanC[1024], rstdC[1024], meanS[1024], rstdS[1024]
//  QF : f16 [b][pix][256]  (pixel-major)
//  KF : f16 [b][pix][256]  (pixel-major)
//  VF : f16 [b][ch][4096]  (channel-major)
//  V2H: f16 [b][ch][4096]  hi part of (f16 V)^2
//  V2L: f16 [b][ch][4096]  lo part (exact hi+lo split)
#define STATS_BYTES (4096 * 4)
#define QF_OFF  (STATS_BYTES)
#define KF_OFF  (QF_OFF + TEN * 2)
#define VF_OFF  (KF_OFF + TEN * 2)
#define V2H_OFF (VF_OFF + TEN * 2)
#define V2L_OFF (V2H_OFF + TEN * 2)

// ---------------------------------------------------------------------------
// Kernel 1: per-(b,c) mean and rstd for content and style. (unchanged)
// ---------------------------------------------------------------------------
__global__ __launch_bounds__(256) void stats_kernel(
    const float* __restrict__ content, const float* __restrict__ style,
    float* __restrict__ ws) {
  int bc = blockIdx.x;
  const float* src = (bc < 1024 ? content : style) + (size_t)(bc & 1023) * HW;
  int t = threadIdx.x;
  const float4* s4 = (const float4*)src;
  float sum = 0.f, ss = 0.f;
#pragma unroll
  for (int n = 0; n < 4; ++n) {
    float4 v = s4[t + n * 256];
    sum += v.x + v.y + v.z + v.w;
    ss += v.x * v.x + v.y * v.y + v.z * v.z + v.w * v.w;
  }
#pragma unroll
  for (int m = 1; m < 64; m <<= 1) {
    sum += __shfl_xor(sum, m, 64);
    ss += __shfl_xor(ss, m, 64);
  }
  __shared__ float redS[4], redQ[4];
  int w = t >> 6;
  if ((t & 63) == 0) { redS[w] = sum; redQ[w] = ss; }
  __syncthreads();
  if (t == 0) {
    float S = redS[0] + redS[1] + redS[2] + redS[3];
    float Q2 = redQ[0] + redQ[1] + redQ[2] + redQ[3];
    float mean = S * (1.0f / HW);
    float var = (Q2 - S * mean) * (1.0f / (HW - 1));
    float rstd = rsqrtf(var + EPSF);
    float* meanArr = ws + (bc < 1024 ? 0 : 2048);
    float* rstdArr = meanArr + 1024;
    meanArr[bc & 1023] = mean;
    rstdArr[bc & 1023] = rstd;
  }
}

// ---------------------------------------------------------------------------
// Kernel 2: fused normalize + 1x1 conv; f16 outputs. (unchanged from r4)
// ---------------------------------------------------------------------------
__global__ __launch_bounds__(256) void proj_kernel(
    const float* __restrict__ content, const float* __restrict__ style,
    const float* __restrict__ Wf, const float* __restrict__ bf,
    const float* __restrict__ Wg, const float* __restrict__ bg,
    const float* __restrict__ Wh, const float* __restrict__ bh,
    char* __restrict__ wsb) {
  float* ws = (float*)wsb;
  int pt = blockIdx.x;
  int ot = blockIdx.y;
  int z = blockIdx.z;
  int tensor = z >> 2, b = z & 3;

  const float* X; const float* Wm; const float* bias;
  const float* meanA = nullptr; const float* rstdA = nullptr;
  if (tensor == 0)      { X = content; Wm = Wf; bias = bf; meanA = ws;        rstdA = ws + 1024; }
  else if (tensor == 1) { X = style;   Wm = Wg; bias = bg; meanA = ws + 2048; rstdA = ws + 3072; }
  else                  { X = style;   Wm = Wh; bias = bh; }

  __shared__ float Xs[32 * 132];
  __shared__ float Wt[32 * 68];

  int t = threadIdx.x;
  int p0 = pt * 128, o0 = ot * 64;
  int o_base = (t >> 4) * 4;
  int p_base = (t & 15) * 8;

  float bb[4];
  { float4 b4 = *(const float4*)&bias[o0 + o_base];
    bb[0] = b4.x; bb[1] = b4.y; bb[2] = b4.z; bb[3] = b4.w; }
  float acc[4][8];
#pragma unroll
  for (int oo = 0; oo < 4; ++oo)
#pragma unroll
    for (int pp = 0; pp < 8; ++pp) acc[oo][pp] = bb[oo];

  const float4* X4 = (const float4*)X;
  const float4* Wm4 = (const float4*)Wm;

  for (int kc = 0; kc < 8; ++kc) {
    int k0 = kc * 32;
    __syncthreads();
#pragma unroll
    for (int n = 0; n < 4; ++n) {
      int f = t + n * 256;
      int kk = f >> 5, p4 = f & 31;
      float4 v = X4[(size_t)(b * NC + k0 + kk) * (HW / 4) + (p0 / 4) + p4];
      if (tensor < 2) {
        float mC = meanA[b * NC + k0 + kk], rC = rstdA[b * NC + k0 + kk];
        v.x = (v.x - mC) * rC; v.y = (v.y - mC) * rC;
        v.z = (v.z - mC) * rC; v.w = (v.w - mC) * rC;
      }
      *(float4*)&Xs[kk * 132 + p4 * 4] = v;
    }
#pragma unroll
    for (int n = 0; n < 2; ++n) {
      int f = t + n * 256;
      int o = f >> 3, k4 = f & 7;
      float4 v = Wm4[(size_t)(o0 + o) * (NC / 4) + kc * 8 + k4];
      Wt[(k4 * 4 + 0) * 68 + o] = v.x;
      Wt[(k4 * 4 + 1) * 68 + o] = v.y;
      Wt[(k4 * 4 + 2) * 68 + o] = v.z;
      Wt[(k4 * 4 + 3) * 68 + o] = v.w;
    }
    __syncthreads();
#pragma unroll
    for (int kk = 0; kk < 32; ++kk) {
      float4 w4 = *(float4*)&Wt[kk * 68 + o_base];
      float4 xa = *(float4*)&Xs[kk * 132 + p_base];
      float4 xb = *(float4*)&Xs[kk * 132 + p_base + 4];
      float wv[4] = {w4.x, w4.y, w4.z, w4.w};
      float xv[8] = {xa.x, xa.y, xa.z, xa.w, xb.x, xb.y, xb.z, xb.w};
#pragma unroll
      for (int oo = 0; oo < 4; ++oo)
#pragma unroll
        for (int pp = 0; pp < 8; ++pp)
          acc[oo][pp] = fmaf(wv[oo], xv[pp], acc[oo][pp]);
    }
  }

  if (tensor < 2) {
    _Float16* dst = (_Float16*)(wsb + (tensor == 0 ? QF_OFF : KF_OFF));
#pragma unroll
    for (int pp = 0; pp < 8; ++pp) {
      half4v h;
      h[0] = (_Float16)acc[0][pp]; h[1] = (_Float16)acc[1][pp];
      h[2] = (_Float16)acc[2][pp]; h[3] = (_Float16)acc[3][pp];
      *(half4v*)&dst[((size_t)(b * HW) + p0 + p_base + pp) * 256 + o0 + o_base] = h;
    }
  } else {
    _Float16* dV  = (_Float16*)(wsb + VF_OFF);
    _Float16* dH  = (_Float16*)(wsb + V2H_OFF);
    _Float16* dL  = (_Float16*)(wsb + V2L_OFF);
#pragma unroll
    for (int oo = 0; oo < 4; ++oo) {
      int ch = o0 + o_base + oo;
      half8 hv, hh, hl;
#pragma unroll
      for (int pp = 0; pp < 8; ++pp) {
        _Float16 vh = (_Float16)acc[oo][pp];
        float vf = (float)vh;
        float v2 = vf * vf;
        _Float16 v2h = (_Float16)v2;
        _Float16 v2l = (_Float16)(v2 - (float)v2h);
        hv[pp] = vh; hh[pp] = v2h; hl[pp] = v2l;
      }
      size_t base = ((size_t)(b * NC) + ch) * HW + p0 + p_base;
      *(half8*)&dV[base] = hv;
      *(half8*)&dH[base] = hh;
      *(half8*)&dL[base] = hl;
    }
  }
}

// ---------------------------------------------------------------------------
// Kernel 3: transposed flash attention, mfma_f32_16x16x32_f16.
// Block = 512 thr = 8 waves = qh(2) x chq(4); q-tile 64, key-tile 32.
// S computed TRANSPOSED (A=K m=key, B=Q n=query) -> softmax reduction is
// 7 in-lane ops + 2 shuffles (r4 had 8-deep shuffle chains x 4 rows).
// PV transposed too (A=V m=ch, B=P n=query); P round-trips through a
// per-wave-PRIVATE 2KB LDS slot (lgkmcnt only, NO barrier).
// 2 barriers/iter (was 4). Global->reg prefetch double-buffer.
// All LDS tiles 16B-granule XOR-swizzled, <=2-way (free) on every pattern.
// ---------------------------------------------------------------------------
__global__ __launch_bounds__(512, 1) void attn_kernel(
    const char* __restrict__ wsb, const float* __restrict__ content,
    float* __restrict__ dout) {
  const _Float16* Qf  = (const _Float16*)(wsb + QF_OFF);
  const _Float16* Kf  = (const _Float16*)(wsb + KF_OFF);
  const _Float16* Vf  = (const _Float16*)(wsb + VF_OFF);
  const _Float16* V2h = (const _Float16*)(wsb + V2H_OFF);
  const _Float16* V2l = (const _Float16*)(wsb + V2L_OFF);
  const float* meanC = (const float*)wsb;
  const float* rstdC = meanC + 1024;

  int qt = blockIdx.x, b = blockIdx.y;
  int t = threadIdx.x;
  int lane = t & 63;
  int w = t >> 6;      // 0..7
  int qh = w >> 2;     // 0..1 : which 32 queries
  int chq = w & 3;     // 0..3 : which 64 channels
  int q0 = qt * 64;
  int ml = lane & 15;
  int kg4 = lane >> 4;

  // LDS: K 16K | V 16K | V2h 16K | V2l 16K | Pt 16K  = 80 KB
  __shared__ int4 smem[5120];
  _Float16* Kb   = (_Float16*)smem;          // [key][256 ch], granule swz g^(key&7)
  _Float16* Vb   = Kb + 8192;                // [ch][32 key], granule swz g^((ch>>1)&3)
  _Float16* V2hb = Kb + 16384;
  _Float16* V2lb = Kb + 24576;
  _Float16* Pw   = Kb + 32768 + w * 1024;    // per-wave private [32 q][32 key]
  int4* Kb4   = (int4*)Kb;
  int4* Vb4   = (int4*)Vb;
  int4* V2hb4 = (int4*)V2hb;
  int4* V2lb4 = (int4*)V2lb;

  // ---- Q B-frags: n=query(ml), k=ch (kg4*8+j); 2 ntiles x 8 kchunks ----
  half8 Bq[2][8];
#pragma unroll
  for (int nt = 0; nt < 2; ++nt)
#pragma unroll
    for (int kc = 0; kc < 8; ++kc) {
      size_t off = ((size_t)(b * HW) + q0 + qh * 32 + nt * 16 + ml) * 256 +
                   kc * 32 + kg4 * 8;
      Bq[nt][kc] = *(const half8*)(Qf + off);
    }

  f32x4 accm[4][2], accs[4][2];  // [ct][nt]: rows=ch, col=query
#pragma unroll
  for (int ct = 0; ct < 4; ++ct)
#pragma unroll
    for (int nt = 0; nt < 2; ++nt) {
      accm[ct][nt] = (f32x4){0.f, 0.f, 0.f, 0.f};
      accs[ct][nt] = (f32x4){0.f, 0.f, 0.f, 0.f};
    }
  float mrun[2] = {-INFINITY, -INFINITY};
  float lrun[2] = {0.f, 0.f};

  // ---- staging geometry ----
  int sk_key = t >> 4;  // 0..31
  int sk_g   = t & 15;  // granules g, g+16
  int sv_k8  = t & 3;   // key granule 0..3
  int sv_ch  = t >> 2;  // 0..127 (+128)
  const int4* Kg   = (const int4*)(Kf  + (size_t)b * HW * 256);
  const int4* Vg   = (const int4*)(Vf  + (size_t)b * NC * HW);
  const int4* V2g  = (const int4*)(V2h + (size_t)b * NC * HW);
  const int4* V2lg = (const int4*)(V2l + (size_t)b * NC * HW);

  int4 pk[2], pv[2], ph2[2], pl2[2];
#pragma unroll
  for (int i = 0; i < 2; ++i) {  // prefetch tile 0
    pk[i] = Kg[(size_t)sk_key * 32 + sk_g + 16 * i];
    int ch = sv_ch + 128 * i;
    size_t gi = (size_t)ch * 512 + sv_k8;
    pv[i] = Vg[gi]; ph2[i] = V2g[gi]; pl2[i] = V2lg[gi];
  }

  for (int kt = 0; kt < 128; ++kt) {
    __syncthreads();  // prev iter's reads of staged bufs complete

    // ---- write staged regs -> LDS (swizzled) ----
#pragma unroll
    for (int i = 0; i < 2; ++i) {
      int g = sk_g + 16 * i;
      Kb4[sk_key * 32 + (g ^ (sk_key & 7))] = pk[i];
      int ch = sv_ch + 128 * i;
      int di = ch * 4 + (sv_k8 ^ ((ch >> 1) & 3));
      Vb4[di] = pv[i]; V2hb4[di] = ph2[i]; V2lb4[di] = pl2[i];
    }
    // ---- prefetch next tile (overlaps this tile's compute) ----
    {
      int ktn = (kt + 1) & 127;
#pragma unroll
      for (int i = 0; i < 2; ++i) {
        pk[i] = Kg[(size_t)(ktn * 32 + sk_key) * 32 + sk_g + 16 * i];
        int ch = sv_ch + 128 * i;
        size_t gi = (size_t)ch * 512 + ktn * 4 + sv_k8;
        pv[i] = Vg[gi]; ph2[i] = V2g[gi]; pl2[i] = V2lg[gi];
      }
    }
    __syncthreads();  // staged tiles visible

    // ---- QK^T transposed: S_T[mt][nt], rows=key, col=query ----
    f32x4 S[2][2];
#pragma unroll
    for (int mt = 0; mt < 2; ++mt)
#pragma unroll
      for (int nt = 0; nt < 2; ++nt) S[mt][nt] = (f32x4){0.f, 0.f, 0.f, 0.f};
#pragma unroll
    for (int kc = 0; kc < 8; ++kc) {
      int g = (kc * 4 + kg4) ^ (ml & 7);
      half8 Ak0 = *(const half8*)(Kb + ml * 256 + g * 8);
      half8 Ak1 = *(const half8*)(Kb + (16 + ml) * 256 + g * 8);
#pragma unroll
      for (int nt = 0; nt < 2; ++nt) {
        S[0][nt] = __builtin_amdgcn_mfma_f32_16x16x32_f16(Ak0, Bq[nt][kc], S[0][nt], 0, 0, 0);
        S[1][nt] = __builtin_amdgcn_mfma_f32_16x16x32_f16(Ak1, Bq[nt][kc], S[1][nt], 0, 0, 0);
      }
    }

    // ---- softmax: per lane 8 keys of its query; 2 shuffles per reduce ----
    bool noup = true;
    float alpha[2];
#pragma unroll
    for (int nt = 0; nt < 2; ++nt) {
      float m8 = S[0][nt][0];
      m8 = fmaxf(m8, S[0][nt][1]); m8 = fmaxf(m8, S[0][nt][2]); m8 = fmaxf(m8, S[0][nt][3]);
      m8 = fmaxf(m8, S[1][nt][0]); m8 = fmaxf(m8, S[1][nt][1]);
      m8 = fmaxf(m8, S[1][nt][2]); m8 = fmaxf(m8, S[1][nt][3]);
      m8 = fmaxf(m8, __shfl_xor(m8, 16, 64));
      m8 = fmaxf(m8, __shfl_xor(m8, 32, 64));
      float mold = mrun[nt];
      float mn = fmaxf(mold, m8);
      alpha[nt] = __expf(mold - mn);
      noup = noup && (mn == mold);
      mrun[nt] = mn;
      half4v p0, p1;
      float rs = 0.f;
#pragma unroll
      for (int r = 0; r < 4; ++r) {
        float pa = __expf(S[0][nt][r] - mn);
        _Float16 pha = (_Float16)pa;
        p0[r] = pha; rs += (float)pha;
        float pb = __expf(S[1][nt][r] - mn);
        _Float16 phb = (_Float16)pb;
        p1[r] = phb; rs += (float)phb;
      }
      rs += __shfl_xor(rs, 16, 64);
      rs += __shfl_xor(rs, 32, 64);
      lrun[nt] = lrun[nt] * alpha[nt] + rs;
      // Pt write (wave-private): keys mt*16+kg4*4+r for query nt*16+ml
      int q = nt * 16 + ml;
      int sw = (q >> 1) & 3;
      *(half4v*)(Pw + q * 32 + (((kg4 >> 1) ^ sw) * 8) + (kg4 & 1) * 4) = p0;
      *(half4v*)(Pw + q * 32 + (((2 + (kg4 >> 1)) ^ sw) * 8) + (kg4 & 1) * 4) = p1;
    }
    if (!__all((int)noup)) {
#pragma unroll
      for (int ct = 0; ct < 4; ++ct)
#pragma unroll
        for (int nt = 0; nt < 2; ++nt)
#pragma unroll
          for (int r = 0; r < 4; ++r) {
            accm[ct][nt][r] *= alpha[nt];
            accs[ct][nt][r] *= alpha[nt];
          }
    }
    __asm__ volatile("s_waitcnt lgkmcnt(0)" ::: "memory");

    // ---- P B-frags: n=query(ml), k=key(kg4*8+j) ----
    half8 Bp[2];
#pragma unroll
    for (int nt = 0; nt < 2; ++nt) {
      int q = nt * 16 + ml;
      Bp[nt] = *(const half8*)(Pw + q * 32 + ((kg4 ^ ((q >> 1) & 3)) * 8));
    }

    // ---- PV: A=V streams (m=ch), B=P; accumulate mean & second ----
#pragma unroll
    for (int ct = 0; ct < 4; ++ct) {
      int ch = chq * 64 + ct * 16 + ml;
      int off = ch * 32 + ((kg4 ^ ((ch >> 1) & 3)) * 8);
      half8 Av = *(const half8*)(Vb + off);
      half8 Ah = *(const half8*)(V2hb + off);
      half8 Al = *(const half8*)(V2lb + off);
#pragma unroll
      for (int nt = 0; nt < 2; ++nt) {
        accm[ct][nt] = __builtin_amdgcn_mfma_f32_16x16x32_f16(Av, Bp[nt], accm[ct][nt], 0, 0, 0);
        accs[ct][nt] = __builtin_amdgcn_mfma_f32_16x16x32_f16(Ah, Bp[nt], accs[ct][nt], 0, 0, 0);
        accs[ct][nt] = __builtin_amdgcn_mfma_f32_16x16x32_f16(Al, Bp[nt], accs[ct][nt], 0, 0, 0);
      }
    }
  }

  // ---- finalize + direct coalesced epilogue (D col = query = ml) ----
  float inv[2] = {1.0f / lrun[0], 1.0f / lrun[1]};
#pragma unroll
  for (int ct = 0; ct < 4; ++ct)
#pragma unroll
    for (int nt = 0; nt < 2; ++nt)
#pragma unroll
      for (int r = 0; r < 4; ++r) {
        int ch = chq * 64 + ct * 16 + kg4 * 4 + r;
        int q = q0 + qh * 32 + nt * 16 + ml;
        float mu = accm[ct][nt][r] * inv[nt];
        float s2 = accs[ct][nt][r] * inv[nt];
        float sd = sqrtf(fmaxf(s2 - mu * mu, 0.f));
        size_t idx = ((size_t)(b * NC) + ch) * HW + q;
        float nc = (content[idx] - meanC[b * NC + ch]) * rstdC[b * NC + ch];
        dout[idx] = sd * nc + mu;
        dout[TEN + idx] = mu;
        dout[2 * TEN + idx] = sd;
      }
}

// ---------------------------------------------------------------------------
extern "C" void kernel_launch(void* const* d_in, const int* in_sizes, int n_in,
                              void* d_out, int out_size, void* d_ws, size_t ws_size,
                              hipStream_t stream) {
  const float* content = (const float*)d_in[0];
  const float* style   = (const float*)d_in[1];
  const float* Wf = (const float*)d_in[2];
  const float* bf = (const float*)d_in[3];
  const float* Wg = (const float*)d_in[4];
  const float* bg = (const float*)d_in[5];
  const float* Wh = (const float*)d_in[6];
  const float* bh = (const float*)d_in[7];
  char* wsb = (char*)d_ws;
  float* out = (float*)d_out;

  hipLaunchKernelGGL(stats_kernel, dim3(2048), dim3(256), 0, stream,
                     content, style, (float*)wsb);
  hipLaunchKernelGGL(proj_kernel, dim3(32, 4, 12), dim3(256), 0, stream,
                     content, style, Wf, bf, Wg, bg, Wh, bh, wsb);
  hipLaunchKernelGGL(attn_kernel, dim3(64, 4), dim3(512), 0, stream,
                     wsb, content, out);
}